// Round 16
// baseline (162.497 us; speedup 1.0000x reference)
//
#include <hip/hip_runtime.h>
#include <math.h>

// Problem constants
#define B_TOT 2048
#define S_LEN 256
#define DIN   3
#define H     128
#define DOUT  6
#define DT_C  0.1f

#define NROWS 4    // batch rows per block -> grid 512 = 2 blocks/CU (2 barrier groups)
#define HPAD  136  // bf16 row stride in sh_h (128 + 8 pad), rows 16B-aligned
#define PPAD  132  // f32 row stride in sh_p (head staging only)

// scale folded into W_hh/W_xh/b_hh so epilogue uses exp2 directly:
// tanh(p) = 1 - 2/(exp2(p * 2*log2e)+1)
#define PRESCALE 2.8853900817779268f   // 2*log2(e)

typedef __attribute__((ext_vector_type(8))) short short8;
typedef __attribute__((ext_vector_type(4))) float f32x4;

__device__ __forceinline__ unsigned short f2bf(float f) {
  unsigned int u = __float_as_uint(f);
  u += 0x7FFFu + ((u >> 16) & 1u);          // round-to-nearest-even
  return (unsigned short)(u >> 16);
}
// pack two f32 -> two bf16 (RNE) in one dword
__device__ __forceinline__ unsigned int pack2_bf16(float a, float b) {
  unsigned int ua = __float_as_uint(a), ub = __float_as_uint(b);
  ua = ua + 0x7FFFu + ((ua >> 16) & 1u);
  ub = ub + 0x7FFFu + ((ub >> 16) & 1u);
  return (ua >> 16) | (ub & 0xFFFF0000u);
}
// DPP row rotate-right by N within each 16-lane row: dst[i] = src[(i-N)&15]
// (AMD convention per the canonical row_shr prefix-scan: shr/ror move data toward
//  HIGHER lane ids. ror:8 is self-inverse, which is why R11/R12 worked either way.)
template <int N>
__device__ __forceinline__ float dpp_ror(float v) {
  int i = __float_as_int(v);
  int r = __builtin_amdgcn_update_dpp(i, i, 0x120 | N, 0xF, 0xF, false);
  return __int_as_float(r);
}

// One block = 4 batch rows, 256 threads (4 waves). Wave w owns j-tile [w*32, w*32+32)
// as TWO m-tiles (t=0,1) sharing B-fragments. Grid 512 = 2 blocks/CU: two
// INDEPENDENT barrier groups interleave on the SIMDs (R6 evidence) on R12's lean body.
//   MFMA: D_t[m=j_loc][n=b]; lane holds (b = lane&15, j_loc = 16t + quad*4 + r); valid b<4.
// DENSE epilogue via DPP row_ror{4,8,12}: lane l owns
//   (b = l16&3, j = w*32 + 16*(g>>1) + quad*4 + 2*(g&1) + {0,1}), g = l16>>2;
//   dst lane 4g+b receives from src lane b  =>  N = 4g.
// B-frag LDS reads exec-masked to l16<4 (masked-out lanes keep once-zeroed regs).
// ONE barrier per step; ping-pong h buffers; step pair shares float2 x loads.
__launch_bounds__(256, 2)
__global__ void ltc_kernel(const float* __restrict__ x,
                           const float* __restrict__ W_xh,
                           const float* __restrict__ W_hh,
                           const float* __restrict__ b_hh,
                           const float* __restrict__ log_tau,
                           const float* __restrict__ fc_W,
                           const float* __restrict__ fc_b,
                           float* __restrict__ out) {
  __shared__ alignas(16) unsigned short sh_h[2][NROWS][HPAD];  // ping-pong h bf16
  __shared__ alignas(16) float sh_p[NROWS][PPAD];              // final h fp32 for head

  const int tid  = threadIdx.x;
  const int w    = tid >> 6;        // wave 0..3 -> j-tile [w*32, w*32+32)
  const int lane = tid & 63;
  const int quad = lane >> 4;       // 0..3
  const int l16  = lane & 15;       // b-column in B/D fragments
  const int rb0  = blockIdx.x * NROWS;

  // ---- zero both h buffers ----
  {
    uint4* p = (uint4*)&sh_h[0][0][0];
    const int n16 = (2 * NROWS * HPAD) / 8;  // shorts -> uint4 count
    for (int i = tid; i < n16; i += 256) p[i] = make_uint4(0, 0, 0, 0);
  }

  // ---- W_hh A-fragments (PRESCALE*W, RNE bf16), register-resident ----
  // A_t[m=l16][k = kc*32 + quad*8 + i],  j = w*32 + 16t + m
  short8 wa[2][4];
#pragma unroll
  for (int t = 0; t < 2; ++t) {
    const int j = w * 32 + t * 16 + l16;
#pragma unroll
    for (int kc = 0; kc < 4; ++kc) {
      const float* src = W_hh + j * H + kc * 32 + quad * 8;
#pragma unroll
      for (int i = 0; i < 8; ++i)
        wa[t][kc][i] = (short)f2bf(src[i] * PRESCALE);
    }
  }

  // ---- dense epilogue mapping ----
  const int brow = l16 & 3;          // batch row 0..3
  const int g    = l16 >> 2;         // 0..3: which (tile, reg-pair) this lane receives
  const int tsel = g >> 1;           // tile 0/1
  const int rp   = g & 1;            // reg-pair 0 (r0,r1) / 1 (r2,r3)
  const int jloc = tsel * 16 + quad * 4 + rp * 2;   // local j of elem 0
  float ewx[2][3], ebh[2], ecc[2], ea[2], encc2[2];
#pragma unroll
  for (int r = 0; r < 2; ++r) {
    const int j = w * 32 + jloc + r;
    ewx[r][0] = W_xh[j * 3 + 0] * PRESCALE;
    ewx[r][1] = W_xh[j * 3 + 1] * PRESCALE;
    ewx[r][2] = W_xh[j * 3 + 2] * PRESCALE;
    ebh[r]    = b_hh[j] * PRESCALE;
    float lt  = log_tau[j];
    float tau = logf(1.f + expf(lt)) + 0.001f;   // softplus + eps, exact fp32, once
    float cc  = DT_C / tau;
    ecc[r]    = cc;
    ea[r]     = 1.f - cc;
    encc2[r]  = -2.f * cc;
  }
  const float* xp = x + (size_t)(rb0 + brow) * (S_LEN * DIN);

  float hreg[2] = {0.f, 0.f};  // fp32 h for (brow, j..j+1), register-resident

  // static LDS offsets (shorts)
  const int rd_off = l16 * HPAD + quad * 8;             // B-frag read (+ kc*32), l16<4 only
  const int wr_off = brow * HPAD + w * 32 + jloc;       // dense 4B h' store
  const unsigned short* __restrict__ buf0 = &sh_h[0][0][0];
  unsigned short* __restrict__ buf1 = &sh_h[1][0][0];

  // persistent B-frag regs: zeroed ONCE; lanes l16>=4 never overwrite them
  short8 bf[4];
#pragma unroll
  for (int kc = 0; kc < 4; ++kc) bf[kc] = short8{0, 0, 0, 0, 0, 0, 0, 0};

  // x prefetch: 6 floats per 2-step pair as 3x float2 (24B step-pair stride)
  float2 pfa = *(const float2*)(xp);
  float2 pfb = *(const float2*)(xp + 2);
  float2 pfc = *(const float2*)(xp + 4);

  __syncthreads();

  auto do_step = [&](const unsigned short* __restrict__ cur,
                     unsigned short* __restrict__ nxt,
                     float xc0, float xc1, float xc2) {
    // B-fragments of h^T (masked; lanes l16>=4 keep zeros)
    if (l16 < NROWS) {
#pragma unroll
      for (int kc = 0; kc < 4; ++kc)
        bf[kc] = *(const short8*)(cur + rd_off + kc * 32);
    }

    // x-projection terms for this lane's 2 elems (hidden under ds_read latency)
    float t0 = __builtin_fmaf(xc2, ewx[0][2], ebh[0]);
    t0 = __builtin_fmaf(xc1, ewx[0][1], t0);
    t0 = __builtin_fmaf(xc0, ewx[0][0], t0);
    float t1 = __builtin_fmaf(xc2, ewx[1][2], ebh[1]);
    t1 = __builtin_fmaf(xc1, ewx[1][1], t1);
    t1 = __builtin_fmaf(xc0, ewx[1][0], t1);

    // two independent 4-deep MFMA chains (m-tiles t=0,1 sharing B-frags)
    f32x4 a0 = {0.f, 0.f, 0.f, 0.f};
    f32x4 a1 = {0.f, 0.f, 0.f, 0.f};
#pragma unroll
    for (int kc = 0; kc < 4; ++kc) {
      a0 = __builtin_amdgcn_mfma_f32_16x16x32_bf16(wa[0][kc], bf[kc], a0, 0, 0, 0);
      a1 = __builtin_amdgcn_mfma_f32_16x16x32_bf16(wa[1][kc], bf[kc], a1, 0, 0, 0);
    }

    // DPP redistribution: value (t, reg, b) lives in lane quad*16+b (b<4).
    // dst lane 4g+b receives from src lane b  =>  row_ror:(4g)  [dst[i]=src[(i-N)&15]]
    float d2 = dpp_ror<4>(a0[2]);     // g=1: (t0, r2/r3)
    float d3 = dpp_ror<4>(a0[3]);
    float e0 = dpp_ror<8>(a1[0]);     // g=2: (t1, r0/r1)
    float e1 = dpp_ror<8>(a1[1]);
    float f2 = dpp_ror<12>(a1[2]);    // g=3: (t1, r2/r3)
    float f3 = dpp_ror<12>(a1[3]);
    float pre0 = (g == 0) ? a0[0] : (g == 1) ? d2 : (g == 2) ? e0 : f2;
    float pre1 = (g == 0) ? a0[1] : (g == 1) ? d3 : (g == 2) ? e1 : f3;

    // dense epilogue: 2 elems/lane, every lane
    {
      float e  = __builtin_amdgcn_exp2f(pre0 + t0);
      float rc = __builtin_amdgcn_rcpf(e + 1.f);
      hreg[0] = __builtin_fmaf(encc2[0], rc, __builtin_fmaf(hreg[0], ea[0], ecc[0]));
    }
    {
      float e  = __builtin_amdgcn_exp2f(pre1 + t1);
      float rc = __builtin_amdgcn_rcpf(e + 1.f);
      hreg[1] = __builtin_fmaf(encc2[1], rc, __builtin_fmaf(hreg[1], ea[1], ecc[1]));
    }

    *(unsigned int*)(nxt + wr_off) = pack2_bf16(hreg[0], hreg[1]);  // dense 4B store
    __syncthreads();
  };

  for (int s = 0; s < S_LEN; s += 2) {
    float2 xa = pfa, xb = pfb, xc = pfc;
    if (s + 2 < S_LEN) {           // uniform branch; prefetch next pair
      xp += 6;
      pfa = *(const float2*)(xp);
      pfb = *(const float2*)(xp + 2);
      pfc = *(const float2*)(xp + 4);
    }
    do_step(buf0, buf1, xa.x, xa.y, xb.x);
    do_step(buf1, (unsigned short*)buf0, xb.y, xc.x, xc.y);
  }

  // ---- final head: params = softplus(h @ fc_W^T + fc_b), [4 x 6] per block ----
  {
    float2 v = make_float2(hreg[0], hreg[1]);
    *(float2*)&sh_p[brow][w * 32 + jloc] = v;   // 8B-aligned, all lanes distinct
  }
  __syncthreads();

  if (tid < NROWS * DOUT) {
    const int b = tid / DOUT;
    const int o = tid - b * DOUT;
    const float* fw = fc_W + o * H;
    float acc = fc_b[o];
#pragma unroll 4
    for (int k = 0; k < H; ++k) acc += sh_p[b][k] * fw[k];
    float sp = (acc > 15.f) ? acc : logf(1.f + expf(acc));
    out[(rb0 + b) * DOUT + o] = sp;
  }
}

extern "C" void kernel_launch(void* const* d_in, const int* in_sizes, int n_in,
                              void* d_out, int out_size, void* d_ws, size_t ws_size,
                              hipStream_t stream) {
  const float* x       = (const float*)d_in[0];
  const float* W_xh    = (const float*)d_in[1];
  const float* W_hh    = (const float*)d_in[2];
  const float* b_hh    = (const float*)d_in[3];
  const float* log_tau = (const float*)d_in[4];
  const float* fc_W    = (const float*)d_in[5];
  const float* fc_b    = (const float*)d_in[6];
  float* out           = (float*)d_out;

  ltc_kernel<<<dim3(B_TOT / NROWS), dim3(256), 0, stream>>>(
      x, W_xh, W_hh, b_hh, log_tau, fc_W, fc_b, out);
}

// Round 17
// 150.752 us; speedup vs baseline: 1.0779x; 1.0779x over previous
//
#include <hip/hip_runtime.h>
#include <math.h>

// Problem constants
#define B_TOT 2048
#define S_LEN 256
#define DIN   3
#define H     128
#define DOUT  6
#define DT_C  0.1f

#define NROWS 8    // batch rows per block (valid cols of the n=16 MFMA face)
#define HPAD  136  // bf16 row stride in sh_h (128 + 8 pad), rows 16B-aligned
#define PPAD  132  // f32 row stride in sh_p (head staging only)

// scale folded into W_hh/W_xh/b_hh so epilogue uses exp2 directly:
// tanh(p) = 1 - 2/(exp2(p * 2*log2e)+1)
#define PRESCALE 2.8853900817779268f   // 2*log2(e)

typedef __attribute__((ext_vector_type(8))) short short8;
typedef __attribute__((ext_vector_type(4))) float f32x4;
typedef __attribute__((ext_vector_type(2))) unsigned int u32x2;

__device__ __forceinline__ unsigned short f2bf(float f) {
  unsigned int u = __float_as_uint(f);
  u += 0x7FFFu + ((u >> 16) & 1u);          // round-to-nearest-even
  return (unsigned short)(u >> 16);
}
// pack two f32 -> two bf16 (RNE) in one dword
__device__ __forceinline__ unsigned int pack2_bf16(float a, float b) {
  unsigned int ua = __float_as_uint(a), ub = __float_as_uint(b);
  ua = ua + 0x7FFFu + ((ua >> 16) & 1u);
  ub = ub + 0x7FFFu + ((ub >> 16) & 1u);
  return (ua >> 16) | (ub & 0xFFFF0000u);
}
// DPP row rotate-right by 8 within each 16-lane row: dst[i] = src[(i-8)&15]
__device__ __forceinline__ float dpp_ror8(float v) {
  int i = __float_as_int(v);
  int r = __builtin_amdgcn_update_dpp(i, i, 0x128, 0xF, 0xF, false);
  return __int_as_float(r);
}

// One block = 8 batch rows, 256 threads (4 waves, 1/SIMD). Wave w owns j-tile
// [w*32, w*32+32) as TWO m-tiles (t=0,1) sharing the SAME B-fragments (h reads
// halve per CU vs the 8-wave version: 16 masked b128/step instead of 32 — the
// LDS burst after each barrier was R12's largest pipe term at ~330 cy).
//   MFMA: D_t[m=j_loc][n=b]; lane holds (b=lane&15, j_loc=16t+quad*4+r); valid b<8.
// DENSE epilogue via one DPP family: tile-1 regs rotate +8 lanes (ror:8);
// lane l owns (b = l16&7, t = l16>>3, j = w*32 + 16t + quad*4 + {0..3}) — 4 elems.
// B-frag LDS reads exec-masked to l16<8; masked-out lanes keep once-zeroed regs.
// ONE barrier per step; ping-pong h buffers; step pair shares float2 x loads.
__launch_bounds__(256, 1)
__global__ void ltc_kernel(const float* __restrict__ x,
                           const float* __restrict__ W_xh,
                           const float* __restrict__ W_hh,
                           const float* __restrict__ b_hh,
                           const float* __restrict__ log_tau,
                           const float* __restrict__ fc_W,
                           const float* __restrict__ fc_b,
                           float* __restrict__ out) {
  __shared__ alignas(16) unsigned short sh_h[2][NROWS][HPAD];  // ping-pong h bf16
  __shared__ alignas(16) float sh_p[NROWS][PPAD];              // final h fp32 for head

  const int tid  = threadIdx.x;
  const int w    = tid >> 6;        // wave 0..3 -> j-tile [w*32, w*32+32)
  const int lane = tid & 63;
  const int quad = lane >> 4;       // 0..3
  const int l16  = lane & 15;       // b-column in B/D fragments
  const int rb0  = blockIdx.x * NROWS;

  // ---- zero both h buffers ----
  {
    uint4* p = (uint4*)&sh_h[0][0][0];
    const int n16 = (2 * NROWS * HPAD) / 8;  // shorts -> uint4 count
    for (int i = tid; i < n16; i += 256) p[i] = make_uint4(0, 0, 0, 0);
  }

  // ---- W_hh A-fragments (PRESCALE*W, RNE bf16), register-resident ----
  // A_t[m=l16][k = kc*32 + quad*8 + i],  j = w*32 + 16t + m
  short8 wa[2][4];
#pragma unroll
  for (int t = 0; t < 2; ++t) {
    const int j = w * 32 + t * 16 + l16;
#pragma unroll
    for (int kc = 0; kc < 4; ++kc) {
      const float* src = W_hh + j * H + kc * 32 + quad * 8;
#pragma unroll
      for (int i = 0; i < 8; ++i)
        wa[t][kc][i] = (short)f2bf(src[i] * PRESCALE);
    }
  }

  // ---- dense epilogue mapping: lane owns (b=l16&7, t=l16>>3, j = w*32+16t+quad*4+r) ----
  const int brow = l16 & 7;
  const int tsel = l16 >> 3;                 // tile this lane's epilogue covers
  const int ej0  = w * 32 + tsel * 16 + quad * 4;
  float ewx[4][3], ebh[4], ecc[4], ea[4], encc2[4];
#pragma unroll
  for (int r = 0; r < 4; ++r) {
    const int j = ej0 + r;
    ewx[r][0] = W_xh[j * 3 + 0] * PRESCALE;
    ewx[r][1] = W_xh[j * 3 + 1] * PRESCALE;
    ewx[r][2] = W_xh[j * 3 + 2] * PRESCALE;
    ebh[r]    = b_hh[j] * PRESCALE;
    float lt  = log_tau[j];
    float tau = logf(1.f + expf(lt)) + 0.001f;   // softplus + eps, exact fp32, once
    float cc  = DT_C / tau;
    ecc[r]    = cc;
    ea[r]     = 1.f - cc;
    encc2[r]  = -2.f * cc;
  }
  const bool t0own = (tsel == 0);
  const float* xp = x + (size_t)(rb0 + brow) * (S_LEN * DIN);

  float hreg[4] = {0.f, 0.f, 0.f, 0.f};  // fp32 h for (brow, ej0..ej0+3)

  // static LDS offsets (shorts)
  const int rd_off = l16 * HPAD + quad * 8;     // B-frag read (+ kc*32), l16<8 only
  const int wr_off = brow * HPAD + ej0;         // dense 8B h' store (4 bf16)
  const unsigned short* __restrict__ buf0 = &sh_h[0][0][0];
  unsigned short* __restrict__ buf1 = &sh_h[1][0][0];

  // persistent B-frag regs: zeroed ONCE; lanes l16>=8 never overwrite them
  short8 bf[4];
#pragma unroll
  for (int kc = 0; kc < 4; ++kc) bf[kc] = short8{0, 0, 0, 0, 0, 0, 0, 0};

  // x prefetch: 6 floats per 2-step pair as 3x float2 (24B step-pair stride)
  float2 pfa = *(const float2*)(xp);
  float2 pfb = *(const float2*)(xp + 2);
  float2 pfc = *(const float2*)(xp + 4);

  __syncthreads();

  auto do_step = [&](const unsigned short* __restrict__ cur,
                     unsigned short* __restrict__ nxt,
                     float xc0, float xc1, float xc2) {
    // B-fragments of h^T (masked; lanes >=8 keep zeros); shared by both m-tiles
    if (l16 < NROWS) {
#pragma unroll
      for (int kc = 0; kc < 4; ++kc)
        bf[kc] = *(const short8*)(cur + rd_off + kc * 32);
    }

    // x-projection terms for this lane's 4 elems (hidden under ds_read latency)
    float t[4];
#pragma unroll
    for (int r = 0; r < 4; ++r) {
      float tt = __builtin_fmaf(xc2, ewx[r][2], ebh[r]);
      tt = __builtin_fmaf(xc1, ewx[r][1], tt);
      t[r] = __builtin_fmaf(xc0, ewx[r][0], tt);
    }

    // two independent 4-deep MFMA chains (m-tiles t=0,1 sharing B-frags)
    f32x4 a0 = {0.f, 0.f, 0.f, 0.f};
    f32x4 a1 = {0.f, 0.f, 0.f, 0.f};
#pragma unroll
    for (int kc = 0; kc < 4; ++kc) {
      a0 = __builtin_amdgcn_mfma_f32_16x16x32_bf16(wa[0][kc], bf[kc], a0, 0, 0, 0);
      a1 = __builtin_amdgcn_mfma_f32_16x16x32_bf16(wa[1][kc], bf[kc], a1, 0, 0, 0);
    }

    // DPP redistribution: tile-1 value (quad,b,r) at lane quad*16+b -> lane quad*16+8+b
    // (ror:8, dst[i]=src[(i-8)&15]); lanes l16<8 keep tile-0 regs.
    float pre[4];
#pragma unroll
    for (int r = 0; r < 4; ++r) {
      float d = dpp_ror8(a1[r]);
      pre[r] = t0own ? a0[r] : d;
    }

    // dense epilogue: 4 elems/lane, every lane
#pragma unroll
    for (int r = 0; r < 4; ++r) {
      float e  = __builtin_amdgcn_exp2f(pre[r] + t[r]);
      float rc = __builtin_amdgcn_rcpf(e + 1.f);
      hreg[r] = __builtin_fmaf(encc2[r], rc, __builtin_fmaf(hreg[r], ea[r], ecc[r]));
    }

    u32x2 hv;
    hv.x = pack2_bf16(hreg[0], hreg[1]);
    hv.y = pack2_bf16(hreg[2], hreg[3]);
    *(u32x2*)(nxt + wr_off) = hv;   // dense 8B store, row b, 4 consecutive j
    __syncthreads();
  };

  for (int s = 0; s < S_LEN; s += 2) {
    float2 xa = pfa, xb = pfb, xc = pfc;
    if (s + 2 < S_LEN) {           // uniform branch; prefetch next pair
      xp += 6;
      pfa = *(const float2*)(xp);
      pfb = *(const float2*)(xp + 2);
      pfc = *(const float2*)(xp + 4);
    }
    do_step(buf0, buf1, xa.x, xa.y, xb.x);
    do_step(buf1, (unsigned short*)buf0, xb.y, xc.x, xc.y);
  }

  // ---- final head: params = softplus(h @ fc_W^T + fc_b), [8 x 6] per block ----
  {
    f32x4 v = {hreg[0], hreg[1], hreg[2], hreg[3]};
    *(f32x4*)&sh_p[brow][ej0] = v;   // 16B-aligned, all lanes distinct
  }
  __syncthreads();

  if (tid < NROWS * DOUT) {
    const int b = tid / DOUT;
    const int o = tid - b * DOUT;
    const float* fw = fc_W + o * H;
    float acc = fc_b[o];
#pragma unroll 4
    for (int k = 0; k < H; ++k) acc += sh_p[b][k] * fw[k];
    float sp = (acc > 15.f) ? acc : logf(1.f + expf(acc));
    out[(rb0 + b) * DOUT + o] = sp;
  }
}

extern "C" void kernel_launch(void* const* d_in, const int* in_sizes, int n_in,
                              void* d_out, int out_size, void* d_ws, size_t ws_size,
                              hipStream_t stream) {
  const float* x       = (const float*)d_in[0];
  const float* W_xh    = (const float*)d_in[1];
  const float* W_hh    = (const float*)d_in[2];
  const float* b_hh    = (const float*)d_in[3];
  const float* log_tau = (const float*)d_in[4];
  const float* fc_W    = (const float*)d_in[5];
  const float* fc_b    = (const float*)d_in[6];
  float* out           = (float*)d_out;

  ltc_kernel<<<dim3(B_TOT / NROWS), dim3(256), 0, stream>>>(
      x, W_xh, W_hh, b_hh, log_tau, fc_W, fc_b, out);
}